// Round 10
// baseline (170.537 us; speedup 1.0000x reference)
//
#include <hip/hip_runtime.h>
#include <hip/hip_bf16.h>

// Sizes fixed by the problem
#define BATCH 4
#define NSEQ  1024
#define DIM   768
#define NH    12
#define NKV   4
#define HD    64
#define NTOK  (BATCH*NSEQ)   // 4096

using bf16 = __hip_bfloat16;
typedef __attribute__((ext_vector_type(8))) short short8;
typedef __attribute__((ext_vector_type(4))) float floatx4;

__device__ __forceinline__ float b2f(short x) {
  unsigned u = ((unsigned)(unsigned short)x) << 16;
  return __builtin_bit_cast(float, u);
}
__device__ __forceinline__ unsigned short f2b(float f) {
  unsigned u = __builtin_bit_cast(unsigned, f);
  unsigned r = u + 0x7FFF + ((u >> 16) & 1);   // RNE
  return (unsigned short)(r >> 16);
}

// async global->LDS, 16B per lane; LDS dest = wave-uniform base + lane*16
__device__ __forceinline__ void load_lds_16(const bf16* g, bf16* l) {
  __builtin_amdgcn_global_load_lds(
      (const __attribute__((address_space(1))) void*)g,
      (__attribute__((address_space(3))) void*)l, 16, 0, 0);
}

// ---------------------------------------------------------------------------
// Fused f32->bf16 convert of all 6 input tensors (exact sizes hardcoded).
// ---------------------------------------------------------------------------
__global__ __launch_bounds__(256) void cvt_all(
    const float* __restrict__ x,  const float* __restrict__ wq,
    const float* __restrict__ wk, const float* __restrict__ wv1,
    const float* __restrict__ wv2, const float* __restrict__ wo,
    bf16* __restrict__ xb,  bf16* __restrict__ wqb, bf16* __restrict__ wkb,
    bf16* __restrict__ wv1b, bf16* __restrict__ wv2b, bf16* __restrict__ wob)
{
  int i = blockIdx.x * 256 + threadIdx.x;   // float4 index, total 1425408
  const float* s; bf16* d; int off;
  if      (i <  786432) { s = x;   d = xb;   off = i; }
  else if (i < 1081344) { s = wq;  d = wqb;  off = i -  786432; }
  else if (i < 1179648) { s = wk;  d = wkb;  off = i - 1081344; }
  else if (i < 1228800) { s = wv1; d = wv1b; off = i - 1179648; }
  else if (i < 1277952) { s = wv2; d = wv2b; off = i - 1228800; }
  else                  { s = wo;  d = wob;  off = i - 1277952; }
  float4 f = reinterpret_cast<const float4*>(s)[off];
  ushort4 u;
  u.x = f2b(f.x); u.y = f2b(f.y); u.z = f2b(f.z); u.w = f2b(f.w);
  reinterpret_cast<ushort4*>(d)[off] = u;
}

// ---------------------------------------------------------------------------
// Fused QKV projection GEMM, 128x128 tile, BK=32, global_load_lds staging.
// grid = (20 N-tiles, 32 M-tiles). N-tiles 0-11: q (rope+norm -> PACKED Qpk),
// 12-15: k (rope+norm -> PACKED Kpk), 16-17: v1, 18-19: v2 (-> packed Vpk).
// Packed layouts match attn fragment order exactly (coalesced lane*16 reads).
// Epilogue rule: no pointer-arg calls (R4 scratch bug); inline __sinf/__cosf,
// constant-index scalars only. NOTE BK stays 32: BK=64 unpadded rows give
// 16-way LDS conflicts on b128 frag reads (row stride 128B ≡ 0 mod 32 banks).
// ---------------------------------------------------------------------------
__global__ __launch_bounds__(256, 2) void gemm_qkv(
    const bf16* __restrict__ xb,
    const bf16* __restrict__ Wqb, const bf16* __restrict__ Wkb,
    const bf16* __restrict__ Wv1b, const bf16* __restrict__ Wv2b,
    bf16* __restrict__ Qpk, bf16* __restrict__ Kpk,
    bf16* __restrict__ Vpk1, bf16* __restrict__ Vpk2)
{
  __shared__ __align__(16) bf16 As[128 * 32];
  __shared__ __align__(16) bf16 Ws[128 * 32];

  const int bn = blockIdx.x, bm = blockIdx.y;
  const bf16* Wp;
  if (bn < 12)      Wp = Wqb  + (size_t)bn * 128 * 768;
  else if (bn < 16) Wp = Wkb  + (size_t)(bn - 12) * 128 * 768;
  else if (bn < 18) Wp = Wv1b + (size_t)(bn - 16) * 128 * 768;
  else              Wp = Wv2b + (size_t)(bn - 18) * 128 * 768;

  const int t = threadIdx.x, wave = t >> 6, lane = t & 63;
  const int wm = wave >> 1, wn = wave & 1;
  const int quad = lane >> 4, lr = lane & 15;

  const int srow = wave * 32 + (lane >> 2);
  const int scol = (lane & 3) * 8;
  const bf16* Ag = xb + (size_t)(bm * 128 + srow) * 768 + scol;
  const bf16* Wg = Wp + (size_t)srow * 768 + scol;
  bf16* Al0 = As + wave * 1024;
  bf16* Al1 = As + wave * 1024 + 512;
  bf16* Wl0 = Ws + wave * 1024;
  bf16* Wl1 = Ws + wave * 1024 + 512;

  floatx4 acc[4][4] = {};

  for (int k0 = 0; k0 < 768; k0 += 32) {
    load_lds_16(Ag + k0,            Al0);
    load_lds_16(Ag + 16 * 768 + k0, Al1);
    load_lds_16(Wg + k0,            Wl0);
    load_lds_16(Wg + 16 * 768 + k0, Wl1);
    __syncthreads();

    short8 af[4], wf[4];
    #pragma unroll
    for (int mt = 0; mt < 4; ++mt)
      af[mt] = *reinterpret_cast<const short8*>(&As[(wm * 64 + mt * 16 + lr) * 32 + quad * 8]);
    #pragma unroll
    for (int nt = 0; nt < 4; ++nt)
      wf[nt] = *reinterpret_cast<const short8*>(&Ws[(wn * 64 + nt * 16 + lr) * 32 + quad * 8]);

    #pragma unroll
    for (int mt = 0; mt < 4; ++mt)
      #pragma unroll
      for (int nt = 0; nt < 4; ++nt)
        acc[mt][nt] = __builtin_amdgcn_mfma_f32_16x16x32_bf16(af[mt], wf[nt], acc[mt][nt], 0, 0, 0);
    __syncthreads();
  }

  // Epilogues. C/D: row = bm*128 + wm*64 + mt*16 + quad*4 + r,
  //                 col(within 128-tile) = wn*64 + nt*16 + lr
  if (bn < 16) {
    // rope + qk-norm (each wave's 64-col chunk = exactly one head; d = nt*16+lr)
    const float K2 = 0.41524101186098309f;             // log2(10000)/32
    const float invf0 = exp2f(-(float)lr * K2);
    const float invf1 = exp2f(-(float)(16 + lr) * K2);
    const float sgn = (lr & 1) ? 1.f : -1.f;
    const bool isq = (bn < 12);
    const int hq = bn * 2 + wn;                        // 0..23 (q)
    const int sq_ = hq / 12, hq_ = hq % 12;
    const int hh = (bn - 12) * 2 + wn;                 // 0..7 (k)
    const int sk_ = hh >> 2, kvh_ = hh & 3;
    const int qk128 = (lr >> 3) * 128;
    #pragma unroll
    for (int mt = 0; mt < 4; ++mt) {
      #pragma unroll
      for (int r = 0; r < 4; ++r) {
        int row = bm * 128 + wm * 64 + mt * 16 + quad * 4 + r;
        int n = row & (NSEQ - 1);
        float ph = (float)(n >> 5), pw = (float)(n & 31);
        float v0 = acc[mt][0][r];
        float v1 = acc[mt][1][r];
        float v2 = acc[mt][2][r];
        float v3 = acc[mt][3][r];
        float rot0 = sgn * __shfl_xor(v0, 1);
        float rot1 = sgn * __shfl_xor(v1, 1);
        float rot2 = sgn * __shfl_xor(v2, 1);
        float rot3 = sgn * __shfl_xor(v3, 1);
        float t0 = ph * invf0, t1 = ph * invf1, t2 = pw * invf0, t3 = pw * invf1;
        float rv0 = v0 * __cosf(t0) + rot0 * __sinf(t0);
        float rv1 = v1 * __cosf(t1) + rot1 * __sinf(t1);
        float rv2 = v2 * __cosf(t2) + rot2 * __sinf(t2);
        float rv3 = v3 * __cosf(t3) + rot3 * __sinf(t3);
        float ss = rv0 * rv0 + rv1 * rv1 + rv2 * rv2 + rv3 * rv3;
        #pragma unroll
        for (int off = 1; off < 16; off <<= 1) ss += __shfl_xor(ss, off);
        float sc = 1.f / (sqrtf(ss) + 1e-6f);
        int bb = row >> 10, kh = n >> 5;               // kh == qh for q
        size_t fo = (size_t)(mt & 1) * 1024 + (quad * 4 + r) * 8 + (lr & 7) + qk128;
        bf16* tb;
        if (isq) {
          tb = Qpk + ((size_t)((bb * 2 + sq_) * 12 + hq_) * 32 + kh) * 2048 + fo;
        } else {
          tb = Kpk + ((size_t)((bb * 2 + sk_) * 4 + kvh_) * 32 + kh) * 2048 + fo;
        }
        *(unsigned short*)&tb[0]   = f2b(rv0 * sc);
        *(unsigned short*)&tb[256] = f2b(rv1 * sc);
        *(unsigned short*)&tb[512] = f2b(rv2 * sc);
        *(unsigned short*)&tb[768] = f2b(rv3 * sc);
      }
    }
  } else {
    // v1/v2: plain epilogue, packed V tiles
    const bool is2 = (bn >= 18);
    bf16* Vp = is2 ? Vpk2 : Vpk1;
    const int kvh_ = (bn - (is2 ? 18 : 16)) * 2 + wn;  // 0..3
    #pragma unroll
    for (int mt = 0; mt < 4; ++mt)
      #pragma unroll
      for (int r = 0; r < 4; ++r) {
        int row = bm * 128 + wm * 64 + mt * 16 + quad * 4 + r;
        int n = row & (NSEQ - 1);
        int bb = row >> 10, kh = n >> 5;
        int rowm = (mt & 1) * 16 + quad * 4 + r;       // row % 32
        int quad_v = rowm >> 3, j = rowm & 7;
        bf16* tb = Vp + ((size_t)(bb * 4 + kvh_) * 32 + kh) * 2048
                   + quad_v * 128 + lr * 8 + j;
        *(unsigned short*)&tb[0]    = f2b(acc[mt][0][r]);
        *(unsigned short*)&tb[512]  = f2b(acc[mt][1][r]);
        *(unsigned short*)&tb[1024] = f2b(acc[mt][2][r]);
        *(unsigned short*)&tb[1536] = f2b(acc[mt][3][r]);
      }
  }
}

// ---------------------------------------------------------------------------
// Final GEMM: out = X @ Wo^T + bo, f32 out, 128x128 tile, global_load_lds.
// ---------------------------------------------------------------------------
__global__ __launch_bounds__(256, 2) void gemm_out(
    const bf16* __restrict__ Xb, const bf16* __restrict__ Wob,
    float* __restrict__ out, const float* __restrict__ bias)
{
  __shared__ __align__(16) bf16 As[128 * 32];
  __shared__ __align__(16) bf16 Ws[128 * 32];

  const int bn = blockIdx.x, bm = blockIdx.y;
  const int t = threadIdx.x, wave = t >> 6, lane = t & 63;
  const int wm = wave >> 1, wn = wave & 1;
  const int quad = lane >> 4, lr = lane & 15;

  const int srow = wave * 32 + (lane >> 2);
  const int scol = (lane & 3) * 8;
  const bf16* Ag = Xb  + (size_t)(bm * 128 + srow) * 768 + scol;
  const bf16* Wg = Wob + (size_t)(bn * 128 + srow) * 768 + scol;
  bf16* Al0 = As + wave * 1024;
  bf16* Al1 = As + wave * 1024 + 512;
  bf16* Wl0 = Ws + wave * 1024;
  bf16* Wl1 = Ws + wave * 1024 + 512;

  floatx4 acc[4][4] = {};

  for (int k0 = 0; k0 < 768; k0 += 32) {
    load_lds_16(Ag + k0,            Al0);
    load_lds_16(Ag + 16 * 768 + k0, Al1);
    load_lds_16(Wg + k0,            Wl0);
    load_lds_16(Wg + 16 * 768 + k0, Wl1);
    __syncthreads();

    short8 af[4], wf[4];
    #pragma unroll
    for (int mt = 0; mt < 4; ++mt)
      af[mt] = *reinterpret_cast<const short8*>(&As[(wm * 64 + mt * 16 + lr) * 32 + quad * 8]);
    #pragma unroll
    for (int nt = 0; nt < 4; ++nt)
      wf[nt] = *reinterpret_cast<const short8*>(&Ws[(wn * 64 + nt * 16 + lr) * 32 + quad * 8]);

    #pragma unroll
    for (int mt = 0; mt < 4; ++mt)
      #pragma unroll
      for (int nt = 0; nt < 4; ++nt)
        acc[mt][nt] = __builtin_amdgcn_mfma_f32_16x16x32_bf16(af[mt], wf[nt], acc[mt][nt], 0, 0, 0);
    __syncthreads();
  }

  #pragma unroll
  for (int nt = 0; nt < 4; ++nt) {
    int col = bn * 128 + wn * 64 + nt * 16 + lr;
    float bv = bias[col];
    #pragma unroll
    for (int mt = 0; mt < 4; ++mt)
      #pragma unroll
      for (int r = 0; r < 4; ++r) {
        int row = bm * 128 + wm * 64 + mt * 16 + quad * 4 + r;
        out[(size_t)row * 768 + col] = acc[mt][nt][r] + bv;
      }
  }
}

// ---------------------------------------------------------------------------
// MFMA flash attention v6: R9 structure, but the kh loop is FIXED-TRIP and
// fully unrolled (half0: 9 steps kh=qh-8..qh; half1: 8 steps kh=qh+1..qh+8).
// Out-of-range kh: clamped load address + zeroed mask word (p=0). This lets
// the compiler software-pipeline loads across steps (the variable-trip while
// loop with breaks blocked unrolling through R9 — attn stuck at ~31 us).
// ---------------------------------------------------------------------------
struct Frag { short8 kf[2][2]; short8 vf[4]; };

__device__ __forceinline__ void attn_load(
    Frag& f, const bf16* __restrict__ kp, const bf16* __restrict__ vp,
    int kh, int lane8)
{
  const bf16* kt = kp + (size_t)kh * 2048 + lane8;
  const bf16* vt = vp + (size_t)kh * 2048 + lane8;
  f.kf[0][0] = *reinterpret_cast<const short8*>(kt);
  f.kf[0][1] = *reinterpret_cast<const short8*>(kt + 512);
  f.kf[1][0] = *reinterpret_cast<const short8*>(kt + 1024);
  f.kf[1][1] = *reinterpret_cast<const short8*>(kt + 1536);
  f.vf[0] = *reinterpret_cast<const short8*>(vt);
  f.vf[1] = *reinterpret_cast<const short8*>(vt + 512);
  f.vf[2] = *reinterpret_cast<const short8*>(vt + 1024);
  f.vf[3] = *reinterpret_cast<const short8*>(vt + 1536);
}

__device__ __forceinline__ void attn_step(
    const short8 (&qf)[2][2], const Frag& f, unsigned maskbits,
    floatx4 (&O)[2][4], float (&psum)[2][4], bf16* __restrict__ Pl,
    int quad, int lr)
{
  floatx4 S[2][2] = {};
  #pragma unroll
  for (int ks = 0; ks < 2; ++ks) {
    S[0][0] = __builtin_amdgcn_mfma_f32_16x16x32_bf16(qf[0][ks], f.kf[0][ks], S[0][0], 0, 0, 0);
    S[0][1] = __builtin_amdgcn_mfma_f32_16x16x32_bf16(qf[0][ks], f.kf[1][ks], S[0][1], 0, 0, 0);
    S[1][0] = __builtin_amdgcn_mfma_f32_16x16x32_bf16(qf[1][ks], f.kf[0][ks], S[1][0], 0, 0, 0);
    S[1][1] = __builtin_amdgcn_mfma_f32_16x16x32_bf16(qf[1][ks], f.kf[1][ks], S[1][1], 0, 0, 0);
  }

  #pragma unroll
  for (int mt = 0; mt < 2; ++mt)
    #pragma unroll
    for (int nt = 0; nt < 2; ++nt)
      #pragma unroll
      for (int r = 0; r < 4; ++r) {
        float p = __expf(S[mt][nt][r] * 0.125f);
        p = ((maskbits >> (mt * 8 + nt * 4 + r)) & 1u) ? p : 0.0f;
        psum[mt][r] += p;
        Pl[(mt * 16 + quad * 4 + r) * 40 + nt * 16 + lr] = __float2bfloat16(p);
      }

  short8 pf0 = *reinterpret_cast<const short8*>(&Pl[(lr) * 40 + quad * 8]);
  short8 pf1 = *reinterpret_cast<const short8*>(&Pl[(16 + lr) * 40 + quad * 8]);
  #pragma unroll
  for (int ntd = 0; ntd < 4; ++ntd) {
    O[0][ntd] = __builtin_amdgcn_mfma_f32_16x16x32_bf16(pf0, f.vf[ntd], O[0][ntd], 0, 0, 0);
    O[1][ntd] = __builtin_amdgcn_mfma_f32_16x16x32_bf16(pf1, f.vf[ntd], O[1][ntd], 0, 0, 0);
  }
}

__device__ __forceinline__ int clamp31(int x) {
  return x < 0 ? 0 : (x > 31 ? 31 : x);
}

template <int N>
__device__ __forceinline__ void attn_run(
    int khstart, const short8 (&qf)[2][2], unsigned maskbits,
    const bf16* __restrict__ kp, const bf16* __restrict__ vp,
    floatx4 (&O)[2][4], float (&psum)[2][4], bf16* __restrict__ Pl,
    int quad, int lr, int lane8)
{
  Frag fA, fB;
  attn_load(fA, kp, vp, clamp31(khstart), lane8);
  if (N > 1) attn_load(fB, kp, vp, clamp31(khstart + 1), lane8);
  #pragma unroll
  for (int j = 0; j < N; ++j) {
    int kh = khstart + j;
    unsigned mb = (kh >= 0 && kh <= 31) ? maskbits : 0u;
    attn_step(qf, (j & 1) ? fB : fA, mb, O, psum, Pl, quad, lr);
    if (j + 2 < N)
      attn_load((j & 1) ? fB : fA, kp, vp, clamp31(khstart + j + 2), lane8);
  }
}

__global__ __launch_bounds__(256, 2) void attn_mfma(
    const bf16* __restrict__ Qpk, const bf16* __restrict__ Kpk,
    const bf16* __restrict__ Vpk1, const bf16* __restrict__ Vpk2,
    const float* __restrict__ lambda_p, bf16* __restrict__ X)
{
  // Loop phase:    [0,10240)  P staging (4 waves x 2560B)
  // Combine phase: O slab [0,8192), psum slab [8192,10240)
  //                Xs [8192,12800) (psum dead by then)
  __shared__ __align__(16) char smem[12800];

  const int bid = blockIdx.x;
  const int qh = bid & 31;
  const int hb = bid >> 5;          // h + 12*b
  const int h  = hb % 12;
  const int b  = hb / 12;
  const int kvh = h / 3;

  const int t = threadIdx.x;
  const int w = t >> 6;             // 0..3
  const int s = w >> 1;             // stream
  const int half = w & 1;           // kh half
  const int lane = t & 63;
  const int quad = lane >> 4, lr = lane & 15;
  const int lane8 = lane * 8;

  bf16* Pl = (bf16*)(smem + w * 2560);
  float* Oslab = (float*)smem;                  // [2048] f32
  float* Pslab = (float*)(smem + 8192);         // [512] f32
  bf16* Xs = (bf16*)(smem + 8192);              // [32][72] bf16

  const int tok0 = b * NSEQ + qh * 32;

  // Q fragments: coalesced from packed tiles
  short8 qf[2][2];
  {
    const bf16* qt = Qpk + ((size_t)((b * 2 + s) * 12 + h) * 32 + qh) * 2048 + lane8;
    qf[0][0] = *reinterpret_cast<const short8*>(qt);
    qf[0][1] = *reinterpret_cast<const short8*>(qt + 512);
    qf[1][0] = *reinterpret_cast<const short8*>(qt + 1024);
    qf[1][1] = *reinterpret_cast<const short8*>(qt + 1536);
  }

  // window mask bits: bit(mt*8+nt*4+r) = |q - km| <= 8
  unsigned maskbits = 0;
  #pragma unroll
  for (int mt = 0; mt < 2; ++mt)
    #pragma unroll
    for (int nt = 0; nt < 2; ++nt)
      #pragma unroll
      for (int r = 0; r < 4; ++r) {
        int qq = mt * 16 + quad * 4 + r;
        int km = nt * 16 + lr;
        int d = km - qq; if (d < 0) d = -d;
        if (d <= 8) maskbits |= 1u << (mt * 8 + nt * 4 + r);
      }

  floatx4 O[2][4] = {};
  float psum[2][4] = {};

  const bf16* kpbase = Kpk + (size_t)((b * 2 + s) * 4 + kvh) * 32 * 2048;
  const bf16* vpbase = (s ? Vpk2 : Vpk1) + (size_t)(b * 4 + kvh) * 32 * 2048;

  // half 0: kh = qh-8 .. qh (9 steps); half 1: kh = qh+1 .. qh+8 (8 steps)
  if (half == 0)
    attn_run<9>(qh - 8, qf, maskbits, kpbase, vpbase, O, psum, Pl, quad, lr, lane8);
  else
    attn_run<8>(qh + 1, qf, maskbits, kpbase, vpbase, O, psum, Pl, quad, lr, lane8);

  // ---- serialized combine through ONE slab (linear partials) ----
  auto writeslab = [&]() {
    #pragma unroll
    for (int mt = 0; mt < 2; ++mt)
      #pragma unroll
      for (int ntd = 0; ntd < 4; ++ntd)
        *reinterpret_cast<floatx4*>(&Oslab[(mt * 4 + ntd) * 256 + lane * 4]) = O[mt][ntd];
    floatx4 p0, p1;
    p0[0] = psum[0][0]; p0[1] = psum[0][1]; p0[2] = psum[0][2]; p0[3] = psum[0][3];
    p1[0] = psum[1][0]; p1[1] = psum[1][1]; p1[2] = psum[1][2]; p1[3] = psum[1][3];
    *reinterpret_cast<floatx4*>(&Pslab[lane * 4])       = p0;
    *reinterpret_cast<floatx4*>(&Pslab[256 + lane * 4]) = p1;
  };
  auto readadd_norm = [&]() {
    #pragma unroll
    for (int mt = 0; mt < 2; ++mt)
      #pragma unroll
      for (int ntd = 0; ntd < 4; ++ntd)
        O[mt][ntd] += *reinterpret_cast<const floatx4*>(&Oslab[(mt * 4 + ntd) * 256 + lane * 4]);
    floatx4 p0 = *reinterpret_cast<const floatx4*>(&Pslab[lane * 4]);
    floatx4 p1 = *reinterpret_cast<const floatx4*>(&Pslab[256 + lane * 4]);
    #pragma unroll
    for (int r = 0; r < 4; ++r) { psum[0][r] += p0[r]; psum[1][r] += p1[r]; }
    #pragma unroll
    for (int off = 1; off < 16; off <<= 1)
      #pragma unroll
      for (int mt = 0; mt < 2; ++mt)
        #pragma unroll
        for (int r = 0; r < 4; ++r)
          psum[mt][r] += __shfl_xor(psum[mt][r], off);
    #pragma unroll
    for (int mt = 0; mt < 2; ++mt)
      #pragma unroll
      for (int r = 0; r < 4; ++r)
        psum[mt][r] = 1.f / psum[mt][r];
    #pragma unroll
    for (int mt = 0; mt < 2; ++mt)
      #pragma unroll
      for (int ntd = 0; ntd < 4; ++ntd)
        #pragma unroll
        for (int r = 0; r < 4; ++r)
          O[mt][ntd][r] *= psum[mt][r];
  };

  __syncthreads();                       // B1: loop done, P staging dead
  if (w == 1) writeslab();               // s0,half1 publishes partials
  __syncthreads();                       // B2
  if (w == 0) readadd_norm();            // s0 total, normalized (in regs)
  __syncthreads();                       // B3: slab free
  if (w == 3) writeslab();               // s1,half1 publishes partials
  __syncthreads();                       // B4
  if (w == 2) {
    readadd_norm();                      // s1 total, normalized
    #pragma unroll
    for (int mt = 0; mt < 2; ++mt)       // publish normalized O2
      #pragma unroll
      for (int ntd = 0; ntd < 4; ++ntd)
        *reinterpret_cast<floatx4*>(&Oslab[(mt * 4 + ntd) * 256 + lane * 4]) = O[mt][ntd];
  }
  __syncthreads();                       // B5
  if (w == 0) {                          // differential combine -> Xs
    float lam = log1pf(__expf(lambda_p[h]));
    #pragma unroll
    for (int mt = 0; mt < 2; ++mt)
      #pragma unroll
      for (int ntd = 0; ntd < 4; ++ntd) {
        floatx4 o2 = *reinterpret_cast<const floatx4*>(&Oslab[(mt * 4 + ntd) * 256 + lane * 4]);
        #pragma unroll
        for (int r = 0; r < 4; ++r) {
          float xv = O[mt][ntd][r] - lam * o2[r];
          Xs[(mt * 16 + quad * 4 + r) * 72 + ntd * 16 + lr] = __float2bfloat16(xv);
        }
      }
  }
  __syncthreads();                       // B6

  // coalesced store of the 32x64 bf16 tile (256 thr = 32 rows x 8 segs)
  {
    int row = t >> 3, seg = t & 7;
    short8 xv = *reinterpret_cast<const short8*>(&Xs[row * 72 + seg * 8]);
    *reinterpret_cast<short8*>(X + (size_t)(tok0 + row) * 768 + h * 64 + seg * 8) = xv;
  }
}

// ---------------------------------------------------------------------------
extern "C" void kernel_launch(void* const* d_in, const int* in_sizes, int n_in,
                              void* d_out, int out_size, void* d_ws, size_t ws_size,
                              hipStream_t stream)
{
  const float* x        = (const float*)d_in[0];
  const float* Wq       = (const float*)d_in[1];
  const float* Wk       = (const float*)d_in[2];
  const float* Wv1      = (const float*)d_in[3];
  const float* Wv2      = (const float*)d_in[4];
  const float* lambda_p = (const float*)d_in[5];
  const float* Wo       = (const float*)d_in[6];
  const float* bo       = (const float*)d_in[7];
  float* out = (float*)d_out;

  bf16* xb   = (bf16*)d_ws;                      // 4096*768
  bf16* Wqb  = xb   + (size_t)NTOK * 768;        // 1536*768
  bf16* Wkb  = Wqb  + (size_t)1536 * 768;        // 512*768
  bf16* Wv1b = Wkb  + (size_t)512 * 768;         // 256*768
  bf16* Wv2b = Wv1b + (size_t)256 * 768;         // 256*768
  bf16* Wob  = Wv2b + (size_t)256 * 768;         // 768*768
  bf16* Qpk  = Wob  + (size_t)768 * 768;         // 3072 tiles * 2048
  bf16* Xb   = Qpk  + (size_t)NTOK * 1536;       // 4096*768
  bf16* Vpk1 = Xb   + (size_t)NTOK * 768;        // 512 tiles * 2048
  bf16* Vpk2 = Vpk1 + (size_t)512 * 2048;        // 512 tiles * 2048
  bf16* Kpk  = Vpk2 + (size_t)512 * 2048;        // 1024 tiles * 2048

  cvt_all<<<5568, 256, 0, stream>>>(x, Wq, Wk, Wv1, Wv2, Wo,
                                    xb, Wqb, Wkb, Wv1b, Wv2b, Wob);

  gemm_qkv<<<dim3(20, 32), 256, 0, stream>>>(xb, Wqb, Wkb, Wv1b, Wv2b,
                                             Qpk, Kpk, Vpk1, Vpk2);

  attn_mfma<<<BATCH * NH * 32, 256, 0, stream>>>(Qpk, Kpk, Vpk1, Vpk2, lambda_p, Xb);

  gemm_out<<<dim3(6, 32), 256, 0, stream>>>(Xb, Wob, out, bo);
}

// Round 11
// 156.470 us; speedup vs baseline: 1.0899x; 1.0899x over previous
//
#include <hip/hip_runtime.h>
#include <hip/hip_bf16.h>

// Sizes fixed by the problem
#define BATCH 4
#define NSEQ  1024
#define DIM   768
#define NH    12
#define NKV   4
#define HD    64
#define NTOK  (BATCH*NSEQ)   // 4096

using bf16 = __hip_bfloat16;
typedef __attribute__((ext_vector_type(8))) short short8;
typedef __attribute__((ext_vector_type(4))) float floatx4;

__device__ __forceinline__ float b2f(short x) {
  unsigned u = ((unsigned)(unsigned short)x) << 16;
  return __builtin_bit_cast(float, u);
}
__device__ __forceinline__ unsigned short f2b(float f) {
  unsigned u = __builtin_bit_cast(unsigned, f);
  unsigned r = u + 0x7FFF + ((u >> 16) & 1);   // RNE
  return (unsigned short)(r >> 16);
}

// async global->LDS, 16B per lane; LDS dest = wave-uniform base + lane*16
__device__ __forceinline__ void load_lds_16(const bf16* g, bf16* l) {
  __builtin_amdgcn_global_load_lds(
      (const __attribute__((address_space(1))) void*)g,
      (__attribute__((address_space(3))) void*)l, 16, 0, 0);
}

// ---------------------------------------------------------------------------
// Fused f32->bf16 convert of all 6 input tensors (exact sizes hardcoded).
// ---------------------------------------------------------------------------
__global__ __launch_bounds__(256) void cvt_all(
    const float* __restrict__ x,  const float* __restrict__ wq,
    const float* __restrict__ wk, const float* __restrict__ wv1,
    const float* __restrict__ wv2, const float* __restrict__ wo,
    bf16* __restrict__ xb,  bf16* __restrict__ wqb, bf16* __restrict__ wkb,
    bf16* __restrict__ wv1b, bf16* __restrict__ wv2b, bf16* __restrict__ wob)
{
  int i = blockIdx.x * 256 + threadIdx.x;   // float4 index, total 1425408
  const float* s; bf16* d; int off;
  if      (i <  786432) { s = x;   d = xb;   off = i; }
  else if (i < 1081344) { s = wq;  d = wqb;  off = i -  786432; }
  else if (i < 1179648) { s = wk;  d = wkb;  off = i - 1081344; }
  else if (i < 1228800) { s = wv1; d = wv1b; off = i - 1179648; }
  else if (i < 1277952) { s = wv2; d = wv2b; off = i - 1228800; }
  else                  { s = wo;  d = wob;  off = i - 1277952; }
  float4 f = reinterpret_cast<const float4*>(s)[off];
  ushort4 u;
  u.x = f2b(f.x); u.y = f2b(f.y); u.z = f2b(f.z); u.w = f2b(f.w);
  reinterpret_cast<ushort4*>(d)[off] = u;
}

// ---------------------------------------------------------------------------
// Fused QKV projection GEMM, 128x128 tile, BK=32, global_load_lds staging.
// grid = (20 N-tiles, 32 M-tiles). N-tiles 0-11: q (rope+norm -> PACKED Qpk),
// 12-15: k (rope+norm -> PACKED Kpk), 16-17: v1, 18-19: v2 (-> packed Vpk).
// Packed layouts match attn fragment order exactly (coalesced lane*16 reads).
// Epilogue rule: no pointer-arg calls (R4 scratch bug); inline __sinf/__cosf,
// constant-index scalars only.
// ---------------------------------------------------------------------------
__global__ __launch_bounds__(256, 2) void gemm_qkv(
    const bf16* __restrict__ xb,
    const bf16* __restrict__ Wqb, const bf16* __restrict__ Wkb,
    const bf16* __restrict__ Wv1b, const bf16* __restrict__ Wv2b,
    bf16* __restrict__ Qpk, bf16* __restrict__ Kpk,
    bf16* __restrict__ Vpk1, bf16* __restrict__ Vpk2)
{
  __shared__ __align__(16) bf16 As[128 * 32];
  __shared__ __align__(16) bf16 Ws[128 * 32];

  const int bn = blockIdx.x, bm = blockIdx.y;
  const bf16* Wp;
  if (bn < 12)      Wp = Wqb  + (size_t)bn * 128 * 768;
  else if (bn < 16) Wp = Wkb  + (size_t)(bn - 12) * 128 * 768;
  else if (bn < 18) Wp = Wv1b + (size_t)(bn - 16) * 128 * 768;
  else              Wp = Wv2b + (size_t)(bn - 18) * 128 * 768;

  const int t = threadIdx.x, wave = t >> 6, lane = t & 63;
  const int wm = wave >> 1, wn = wave & 1;
  const int quad = lane >> 4, lr = lane & 15;

  const int srow = wave * 32 + (lane >> 2);
  const int scol = (lane & 3) * 8;
  const bf16* Ag = xb + (size_t)(bm * 128 + srow) * 768 + scol;
  const bf16* Wg = Wp + (size_t)srow * 768 + scol;
  bf16* Al0 = As + wave * 1024;
  bf16* Al1 = As + wave * 1024 + 512;
  bf16* Wl0 = Ws + wave * 1024;
  bf16* Wl1 = Ws + wave * 1024 + 512;

  floatx4 acc[4][4] = {};

  for (int k0 = 0; k0 < 768; k0 += 32) {
    load_lds_16(Ag + k0,            Al0);
    load_lds_16(Ag + 16 * 768 + k0, Al1);
    load_lds_16(Wg + k0,            Wl0);
    load_lds_16(Wg + 16 * 768 + k0, Wl1);
    __syncthreads();

    short8 af[4], wf[4];
    #pragma unroll
    for (int mt = 0; mt < 4; ++mt)
      af[mt] = *reinterpret_cast<const short8*>(&As[(wm * 64 + mt * 16 + lr) * 32 + quad * 8]);
    #pragma unroll
    for (int nt = 0; nt < 4; ++nt)
      wf[nt] = *reinterpret_cast<const short8*>(&Ws[(wn * 64 + nt * 16 + lr) * 32 + quad * 8]);

    #pragma unroll
    for (int mt = 0; mt < 4; ++mt)
      #pragma unroll
      for (int nt = 0; nt < 4; ++nt)
        acc[mt][nt] = __builtin_amdgcn_mfma_f32_16x16x32_bf16(af[mt], wf[nt], acc[mt][nt], 0, 0, 0);
    __syncthreads();
  }

  // Epilogues. C/D: row = bm*128 + wm*64 + mt*16 + quad*4 + r,
  //                 col(within 128-tile) = wn*64 + nt*16 + lr
  if (bn < 16) {
    const float K2 = 0.41524101186098309f;             // log2(10000)/32
    const float invf0 = exp2f(-(float)lr * K2);
    const float invf1 = exp2f(-(float)(16 + lr) * K2);
    const float sgn = (lr & 1) ? 1.f : -1.f;
    const bool isq = (bn < 12);
    const int hq = bn * 2 + wn;                        // 0..23 (q)
    const int sq_ = hq / 12, hq_ = hq % 12;
    const int hh = (bn - 12) * 2 + wn;                 // 0..7 (k)
    const int sk_ = hh >> 2, kvh_ = hh & 3;
    const int qk128 = (lr >> 3) * 128;
    #pragma unroll
    for (int mt = 0; mt < 4; ++mt) {
      #pragma unroll
      for (int r = 0; r < 4; ++r) {
        int row = bm * 128 + wm * 64 + mt * 16 + quad * 4 + r;
        int n = row & (NSEQ - 1);
        float ph = (float)(n >> 5), pw = (float)(n & 31);
        float v0 = acc[mt][0][r];
        float v1 = acc[mt][1][r];
        float v2 = acc[mt][2][r];
        float v3 = acc[mt][3][r];
        float rot0 = sgn * __shfl_xor(v0, 1);
        float rot1 = sgn * __shfl_xor(v1, 1);
        float rot2 = sgn * __shfl_xor(v2, 1);
        float rot3 = sgn * __shfl_xor(v3, 1);
        float t0 = ph * invf0, t1 = ph * invf1, t2 = pw * invf0, t3 = pw * invf1;
        float rv0 = v0 * __cosf(t0) + rot0 * __sinf(t0);
        float rv1 = v1 * __cosf(t1) + rot1 * __sinf(t1);
        float rv2 = v2 * __cosf(t2) + rot2 * __sinf(t2);
        float rv3 = v3 * __cosf(t3) + rot3 * __sinf(t3);
        float ss = rv0 * rv0 + rv1 * rv1 + rv2 * rv2 + rv3 * rv3;
        #pragma unroll
        for (int off = 1; off < 16; off <<= 1) ss += __shfl_xor(ss, off);
        float sc = 1.f / (sqrtf(ss) + 1e-6f);
        int bb = row >> 10, kh = n >> 5;               // kh == qh for q
        size_t fo = (size_t)(mt & 1) * 1024 + (quad * 4 + r) * 8 + (lr & 7) + qk128;
        bf16* tb;
        if (isq) {
          tb = Qpk + ((size_t)((bb * 2 + sq_) * 12 + hq_) * 32 + kh) * 2048 + fo;
        } else {
          tb = Kpk + ((size_t)((bb * 2 + sk_) * 4 + kvh_) * 32 + kh) * 2048 + fo;
        }
        *(unsigned short*)&tb[0]   = f2b(rv0 * sc);
        *(unsigned short*)&tb[256] = f2b(rv1 * sc);
        *(unsigned short*)&tb[512] = f2b(rv2 * sc);
        *(unsigned short*)&tb[768] = f2b(rv3 * sc);
      }
    }
  } else {
    const bool is2 = (bn >= 18);
    bf16* Vp = is2 ? Vpk2 : Vpk1;
    const int kvh_ = (bn - (is2 ? 18 : 16)) * 2 + wn;  // 0..3
    #pragma unroll
    for (int mt = 0; mt < 4; ++mt)
      #pragma unroll
      for (int r = 0; r < 4; ++r) {
        int row = bm * 128 + wm * 64 + mt * 16 + quad * 4 + r;
        int n = row & (NSEQ - 1);
        int bb = row >> 10, kh = n >> 5;
        int rowm = (mt & 1) * 16 + quad * 4 + r;       // row % 32
        int quad_v = rowm >> 3, j = rowm & 7;
        bf16* tb = Vp + ((size_t)(bb * 4 + kvh_) * 32 + kh) * 2048
                   + quad_v * 128 + lr * 8 + j;
        *(unsigned short*)&tb[0]    = f2b(acc[mt][0][r]);
        *(unsigned short*)&tb[512]  = f2b(acc[mt][1][r]);
        *(unsigned short*)&tb[1024] = f2b(acc[mt][2][r]);
        *(unsigned short*)&tb[1536] = f2b(acc[mt][3][r]);
      }
  }
}

// ---------------------------------------------------------------------------
// Final GEMM: out = X @ Wo^T + bo, f32 out. 64x64 tiles, grid (12,64) = 768
// blocks = 3 blocks/CU (the 128-tile version had 192 blocks = 0.75/CU —
// parallelism-starved for a 4.8 GF GEMM). 8 KB LDS, light VGPR.
// ---------------------------------------------------------------------------
__global__ __launch_bounds__(256) void gemm_out(
    const bf16* __restrict__ Xb, const bf16* __restrict__ Wob,
    float* __restrict__ out, const float* __restrict__ bias)
{
  __shared__ __align__(16) bf16 As[64 * 32];
  __shared__ __align__(16) bf16 Ws[64 * 32];

  const int bn = blockIdx.x, bm = blockIdx.y;
  const int t = threadIdx.x, wave = t >> 6, lane = t & 63;
  const int wm = wave >> 1, wn = wave & 1;
  const int quad = lane >> 4, lr = lane & 15;

  // staging: wave stages 16 rows of each tile (64 lanes x 16B = 1024B chunk)
  const int srow = wave * 16 + (lane >> 2);
  const int scol = (lane & 3) * 8;
  const bf16* Ag = Xb  + (size_t)(bm * 64 + srow) * 768 + scol;
  const bf16* Wg = Wob + (size_t)(bn * 64 + srow) * 768 + scol;
  bf16* Al = As + wave * 512;
  bf16* Wl = Ws + wave * 512;

  floatx4 acc[2][2] = {};

  for (int k0 = 0; k0 < 768; k0 += 32) {
    load_lds_16(Ag + k0, Al);
    load_lds_16(Wg + k0, Wl);
    __syncthreads();

    short8 af[2], wf[2];
    #pragma unroll
    for (int mt = 0; mt < 2; ++mt)
      af[mt] = *reinterpret_cast<const short8*>(&As[(wm * 32 + mt * 16 + lr) * 32 + quad * 8]);
    #pragma unroll
    for (int nt = 0; nt < 2; ++nt)
      wf[nt] = *reinterpret_cast<const short8*>(&Ws[(wn * 32 + nt * 16 + lr) * 32 + quad * 8]);

    #pragma unroll
    for (int mt = 0; mt < 2; ++mt)
      #pragma unroll
      for (int nt = 0; nt < 2; ++nt)
        acc[mt][nt] = __builtin_amdgcn_mfma_f32_16x16x32_bf16(af[mt], wf[nt], acc[mt][nt], 0, 0, 0);
    __syncthreads();
  }

  #pragma unroll
  for (int nt = 0; nt < 2; ++nt) {
    int col = bn * 64 + wn * 32 + nt * 16 + lr;
    float bv = bias[col];
    #pragma unroll
    for (int mt = 0; mt < 2; ++mt)
      #pragma unroll
      for (int r = 0; r < 4; ++r) {
        int row = bm * 64 + wm * 32 + mt * 16 + quad * 4 + r;
        out[(size_t)row * 768 + col] = acc[mt][nt][r] + bv;
      }
  }
}

// ---------------------------------------------------------------------------
// MFMA flash attention (R9 config — empirical optimum: 4 waves = stream x
// kh-half, variable-trip loop, 76 VGPR / 6 waves/SIMD, coalesced packed
// Q/K/V tiles, 12800 B LDS). R10's fixed-trip unroll regressed (VGPR 112 ->
// 4 waves/SIMD); 8-way split regressed (per-wave fixed costs). Do not touch.
// ---------------------------------------------------------------------------
struct Frag { short8 kf[2][2]; short8 vf[4]; };

__device__ __forceinline__ void attn_load(
    Frag& f, const bf16* __restrict__ kp, const bf16* __restrict__ vp,
    int kh, int lane8)
{
  const bf16* kt = kp + (size_t)kh * 2048 + lane8;
  const bf16* vt = vp + (size_t)kh * 2048 + lane8;
  f.kf[0][0] = *reinterpret_cast<const short8*>(kt);
  f.kf[0][1] = *reinterpret_cast<const short8*>(kt + 512);
  f.kf[1][0] = *reinterpret_cast<const short8*>(kt + 1024);
  f.kf[1][1] = *reinterpret_cast<const short8*>(kt + 1536);
  f.vf[0] = *reinterpret_cast<const short8*>(vt);
  f.vf[1] = *reinterpret_cast<const short8*>(vt + 512);
  f.vf[2] = *reinterpret_cast<const short8*>(vt + 1024);
  f.vf[3] = *reinterpret_cast<const short8*>(vt + 1536);
}

__device__ __forceinline__ void attn_step(
    const short8 (&qf)[2][2], const Frag& f, unsigned maskbits,
    floatx4 (&O)[2][4], float (&psum)[2][4], bf16* __restrict__ Pl,
    int quad, int lr)
{
  floatx4 S[2][2] = {};
  #pragma unroll
  for (int ks = 0; ks < 2; ++ks) {
    S[0][0] = __builtin_amdgcn_mfma_f32_16x16x32_bf16(qf[0][ks], f.kf[0][ks], S[0][0], 0, 0, 0);
    S[0][1] = __builtin_amdgcn_mfma_f32_16x16x32_bf16(qf[0][ks], f.kf[1][ks], S[0][1], 0, 0, 0);
    S[1][0] = __builtin_amdgcn_mfma_f32_16x16x32_bf16(qf[1][ks], f.kf[0][ks], S[1][0], 0, 0, 0);
    S[1][1] = __builtin_amdgcn_mfma_f32_16x16x32_bf16(qf[1][ks], f.kf[1][ks], S[1][1], 0, 0, 0);
  }

  #pragma unroll
  for (int mt = 0; mt < 2; ++mt)
    #pragma unroll
    for (int nt = 0; nt < 2; ++nt)
      #pragma unroll
      for (int r = 0; r < 4; ++r) {
        float p = __expf(S[mt][nt][r] * 0.125f);
        p = ((maskbits >> (mt * 8 + nt * 4 + r)) & 1u) ? p : 0.0f;
        psum[mt][r] += p;
        *(unsigned short*)&Pl[(mt * 16 + quad * 4 + r) * 40 + nt * 16 + lr] = f2b(p);
      }

  short8 pf0 = *reinterpret_cast<const short8*>(&Pl[(lr) * 40 + quad * 8]);
  short8 pf1 = *reinterpret_cast<const short8*>(&Pl[(16 + lr) * 40 + quad * 8]);
  #pragma unroll
  for (int ntd = 0; ntd < 4; ++ntd) {
    O[0][ntd] = __builtin_amdgcn_mfma_f32_16x16x32_bf16(pf0, f.vf[ntd], O[0][ntd], 0, 0, 0);
    O[1][ntd] = __builtin_amdgcn_mfma_f32_16x16x32_bf16(pf1, f.vf[ntd], O[1][ntd], 0, 0, 0);
  }
}

__global__ __launch_bounds__(256, 2) void attn_mfma(
    const bf16* __restrict__ Qpk, const bf16* __restrict__ Kpk,
    const bf16* __restrict__ Vpk1, const bf16* __restrict__ Vpk2,
    const float* __restrict__ lambda_p, bf16* __restrict__ X)
{
  // Loop phase:    [0,10240)  P staging (4 waves x 2560B)
  // Combine phase: O slab [0,8192), psum slab [8192,10240)
  //                Xs [8192,12800) (psum dead by then)
  __shared__ __align__(16) char smem[12800];

  const int bid = blockIdx.x;
  const int qh = bid & 31;
  const int hb = bid >> 5;          // h + 12*b
  const int h  = hb % 12;
  const int b  = hb / 12;
  const int kvh = h / 3;

  const int t = threadIdx.x;
  const int w = t >> 6;             // 0..3
  const int s = w >> 1;             // stream
  const int half = w & 1;           // kh half
  const int lane = t & 63;
  const int quad = lane >> 4, lr = lane & 15;
  const int lane8 = lane * 8;

  bf16* Pl = (bf16*)(smem + w * 2560);
  float* Oslab = (float*)smem;                  // [2048] f32
  float* Pslab = (float*)(smem + 8192);         // [512] f32
  bf16* Xs = (bf16*)(smem + 8192);              // [32][72] bf16

  const int tok0 = b * NSEQ + qh * 32;

  // Q fragments: coalesced from packed tiles
  short8 qf[2][2];
  {
    const bf16* qt = Qpk + ((size_t)((b * 2 + s) * 12 + h) * 32 + qh) * 2048 + lane8;
    qf[0][0] = *reinterpret_cast<const short8*>(qt);
    qf[0][1] = *reinterpret_cast<const short8*>(qt + 512);
    qf[1][0] = *reinterpret_cast<const short8*>(qt + 1024);
    qf[1][1] = *reinterpret_cast<const short8*>(qt + 1536);
  }

  // window mask bits: bit(mt*8+nt*4+r) = |q - km| <= 8
  unsigned maskbits = 0;
  #pragma unroll
  for (int mt = 0; mt < 2; ++mt)
    #pragma unroll
    for (int nt = 0; nt < 2; ++nt)
      #pragma unroll
      for (int r = 0; r < 4; ++r) {
        int qq = mt * 16 + quad * 4 + r;
        int km = nt * 16 + lr;
        int d = km - qq; if (d < 0) d = -d;
        if (d <= 8) maskbits |= 1u << (mt * 8 + nt * 4 + r);
      }

  floatx4 O[2][4] = {};
  float psum[2][4] = {};

  const int kh0 = (qh > 8) ? qh - 8 : 0;
  const int kh1 = (qh < 23) ? qh + 8 : 31;
  const int cnt = kh1 - kh0 + 1;              // 9..17 -> both halves nonempty
  const int cA = (cnt + 1) >> 1;
  const int khA = half ? kh0 + cA : kh0;
  const int khB = half ? kh1 : kh0 + cA - 1;

  const bf16* kpbase = Kpk + (size_t)((b * 2 + s) * 4 + kvh) * 32 * 2048;
  const bf16* vpbase = (s ? Vpk2 : Vpk1) + (size_t)(b * 4 + kvh) * 32 * 2048;

  Frag fA, fB;
  attn_load(fA, kpbase, vpbase, khA, lane8);
  attn_load(fB, kpbase, vpbase, (khA + 1 <= khB) ? khA + 1 : khB, lane8);

  int i = khA;
  while (true) {
    attn_step(qf, fA, maskbits, O, psum, Pl, quad, lr);
    if (i == khB) break;
    ++i;
    attn_load(fA, kpbase, vpbase, (i + 1 <= khB) ? i + 1 : i, lane8);
    attn_step(qf, fB, maskbits, O, psum, Pl, quad, lr);
    if (i == khB) break;
    ++i;
    attn_load(fB, kpbase, vpbase, (i + 1 <= khB) ? i + 1 : i, lane8);
  }

  // ---- serialized combine through ONE slab (linear partials) ----
  auto writeslab = [&]() {
    #pragma unroll
    for (int mt = 0; mt < 2; ++mt)
      #pragma unroll
      for (int ntd = 0; ntd < 4; ++ntd)
        *reinterpret_cast<floatx4*>(&Oslab[(mt * 4 + ntd) * 256 + lane * 4]) = O[mt][ntd];
    floatx4 p0, p1;
    p0[0] = psum[0][0]; p0[1] = psum[0][1]; p0[2] = psum[0][2]; p0[3] = psum[0][3];
    p1[0] = psum[1][0]; p1[1] = psum[1][1]; p1[2] = psum[1][2]; p1[3] = psum[1][3];
    *reinterpret_cast<floatx4*>(&Pslab[lane * 4])       = p0;
    *reinterpret_cast<floatx4*>(&Pslab[256 + lane * 4]) = p1;
  };
  auto readadd_norm = [&]() {
    #pragma unroll
    for (int mt = 0; mt < 2; ++mt)
      #pragma unroll
      for (int ntd = 0; ntd < 4; ++ntd)
        O[mt][ntd] += *reinterpret_cast<const floatx4*>(&Oslab[(mt * 4 + ntd) * 256 + lane * 4]);
    floatx4 p0 = *reinterpret_cast<const floatx4*>(&Pslab[lane * 4]);
    floatx4 p1 = *reinterpret_cast<const floatx4*>(&Pslab[256 + lane * 4]);
    #pragma unroll
    for (int r = 0; r < 4; ++r) { psum[0][r] += p0[r]; psum[1][r] += p1[r]; }
    #pragma unroll
    for (int off = 1; off < 16; off <<= 1)
      #pragma unroll
      for (int mt = 0; mt < 2; ++mt)
        #pragma unroll
        for (int r = 0; r < 4; ++r)
          psum[mt][r] += __shfl_xor(psum[mt][r], off);
    #pragma unroll
    for (int mt = 0; mt < 2; ++mt)
      #pragma unroll
      for (int r = 0; r < 4; ++r)
        psum[mt][r] = 1.f / psum[mt][r];
    #pragma unroll
    for (int mt = 0; mt < 2; ++mt)
      #pragma unroll
      for (int ntd = 0; ntd < 4; ++ntd)
        #pragma unroll
        for (int r = 0; r < 4; ++r)
          O[mt][ntd][r] *= psum[mt][r];
  };

  __syncthreads();                       // B1: loop done, P staging dead
  if (w == 1) writeslab();               // s0,half1 publishes partials
  __syncthreads();                       // B2
  if (w == 0) readadd_norm();            // s0 total, normalized (in regs)
  __syncthreads();                       // B3: slab free
  if (w == 3) writeslab();               // s1,half1 publishes partials
  __syncthreads();                       // B4
  if (w == 2) {
    readadd_norm();                      // s1 total, normalized
    #pragma unroll
    for (int mt = 0; mt < 2; ++mt)       // publish normalized O2
      #pragma unroll
      for (int ntd = 0; ntd < 4; ++ntd)
        *reinterpret_cast<floatx4*>(&Oslab[(mt * 4 + ntd) * 256 + lane * 4]) = O[mt][ntd];
  }
  __syncthreads();                       // B5
  if (w == 0) {                          // differential combine -> Xs
    float lam = log1pf(__expf(lambda_p[h]));
    #pragma unroll
    for (int mt = 0; mt < 2; ++mt)
      #pragma unroll
      for (int ntd = 0; ntd < 4; ++ntd) {
        floatx4 o2 = *reinterpret_cast<const floatx4*>(&Oslab[(mt * 4 + ntd) * 256 + lane * 4]);
        #pragma unroll
        for (int r = 0; r < 4; ++r) {
          float xv = O[mt][ntd][r] - lam * o2[r];
          *(unsigned short*)&Xs[(mt * 16 + quad * 4 + r) * 72 + ntd * 16 + lr] = f2b(xv);
        }
      }
  }
  __syncthreads();                       // B6

  // coalesced store of the 32x64 bf16 tile (256 thr = 32 rows x 8 segs)
  {
    int row = t >> 3, seg = t & 7;
    short8 xv = *reinterpret_cast<const short8*>(&Xs[row * 72 + seg * 8]);
    *reinterpret_cast<short8*>(X + (size_t)(tok0 + row) * 768 + h * 64 + seg * 8) = xv;
  }
}

// ---------------------------------------------------------------------------
extern "C" void kernel_launch(void* const* d_in, const int* in_sizes, int n_in,
                              void* d_out, int out_size, void* d_ws, size_t ws_size,
                              hipStream_t stream)
{
  const float* x        = (const float*)d_in[0];
  const float* Wq       = (const float*)d_in[1];
  const float* Wk       = (const float*)d_in[2];
  const float* Wv1      = (const float*)d_in[3];
  const float* Wv2      = (const float*)d_in[4];
  const float* lambda_p = (const float*)d_in[5];
  const float* Wo       = (const float*)d_in[6];
  const float* bo       = (const float*)d_in[7];
  float* out = (float*)d_out;

  bf16* xb   = (bf16*)d_ws;                      // 4096*768
  bf16* Wqb  = xb   + (size_t)NTOK * 768;        // 1536*768
  bf16* Wkb  = Wqb  + (size_t)1536 * 768;        // 512*768
  bf16* Wv1b = Wkb  + (size_t)512 * 768;         // 256*768
  bf16* Wv2b = Wv1b + (size_t)256 * 768;         // 256*768
  bf16* Wob  = Wv2b + (size_t)256 * 768;         // 768*768
  bf16* Qpk  = Wob  + (size_t)768 * 768;         // 3072 tiles * 2048
  bf16* Xb   = Qpk  + (size_t)NTOK * 1536;       // 4096*768
  bf16* Vpk1 = Xb   + (size_t)NTOK * 768;        // 512 tiles * 2048
  bf16* Vpk2 = Vpk1 + (size_t)512 * 2048;        // 512 tiles * 2048
  bf16* Kpk  = Vpk2 + (size_t)512 * 2048;        // 1024 tiles * 2048

  cvt_all<<<5568, 256, 0, stream>>>(x, Wq, Wk, Wv1, Wv2, Wo,
                                    xb, Wqb, Wkb, Wv1b, Wv2b, Wob);

  gemm_qkv<<<dim3(20, 32), 256, 0, stream>>>(xb, Wqb, Wkb, Wv1b, Wv2b,
                                             Qpk, Kpk, Vpk1, Vpk2);

  attn_mfma<<<BATCH * NH * 32, 256, 0, stream>>>(Qpk, Kpk, Vpk1, Vpk2, lambda_p, Xb);

  gemm_out<<<dim3(12, 64), 256, 0, stream>>>(Xb, Wob, out, bo);
}